// Round 4
// baseline (318.384 us; speedup 1.0000x reference)
//
#include <hip/hip_runtime.h>
#include <stdint.h>

// Batched tiny MLP [B,13]->16->(30x 16->16 relu)->1, fp32 in/out, f16 MFMA.
// Transposed formulation: mfma_f32_16x16x16_f16 D layout == B layout, so each
// layer's relu'd output is the next layer's B fragment in-register.
// R16: pin the register budget. R15 proved the spill is the ALLOCATOR'S
// choice, not a hard cap: launch_bounds(512,4) allows 128 VGPRs but only
// sets a MINIMUM of 4 waves/EU -- LLVM chased 8 waves/EU, clamped to 64
// VGPRs, and spilled v[8]+bf[8] (54 dwords/lane-iter: WRITE_SIZE 237MB vs
// 8.4MB of real output, FETCH +233MB of re-reads). Fix: degenerate range
// __attribute__((amdgpu_waves_per_eu(4,4))) -- allocator may no longer
// trade regs for occupancy; must use up to 128 regs @ 4 waves/SIMD.
// Live set ~100 regs (v[8]=32 across chain, bf[8]=16, d in flight, a/c
// prefetch 18, addr ~10) fits. Structure unchanged from R15: direct
// coalesced dwordx4 gather (no LDS x round-trip, 0 bank conflicts), relu
// fused into MFMA loop, T=8 chains/wave for ILP, cross-sweep prefetch.
// Floors: MFMA ~28us, memory ~19us. Target 40-55us.
// Edge case: lane(col=15,g=3) k0=12 gather would read 2 dwords past x's end
// on the last tile (x is exactly 2097152*52B). That lane loads shifted by -3
// dwords and selects v[3] as k=12, zeros for k>=13 (A rows 13..15 are zero,
// but garbage must be FINITE, so force 0).

typedef __attribute__((ext_vector_type(4))) _Float16 half4v;
typedef __attribute__((ext_vector_type(2))) _Float16 h2;
typedef __attribute__((ext_vector_type(4))) float float4v;

#define S_IN 13
#define H 16
#define NL 32            // mfma layers: 0 = input, 1..30 = hidden, 31 = output
#define TPB 512
#define WPB 8            // waves per block
#define T 8              // 16-sample tiles per wave per iteration
#define NBLOCKS 512      // 2 blocks/CU * 256 CUs
#define STRIDE (NBLOCKS * WPB * T)   // tiles per grid sweep = 32768

// LDS dword map (weights/bias only):
//   [0, 4096)     A-frags: 2 dwords (4 f16) per (L, lane)
//   [4096, 4608)  bias[L][m] fp32 (C-operand order)
#define LDS_DW 4608

__device__ __forceinline__ unsigned pkh(float a, float b) {
    return __builtin_bit_cast(unsigned, __builtin_amdgcn_cvt_pkrtz(a, b));
}

__device__ __forceinline__ half4v pack4h(float v0, float v1, float v2, float v3) {
    int2 p;
    p.x = (int)pkh(v0, v1);
    p.y = (int)pkh(v2, v3);
    return __builtin_bit_cast(half4v, p);
}

// cvt then packed-f16 relu: 2 cvt + 2 v_pk_max_f16
__device__ __forceinline__ half4v relu_pack4h(const float4v& d) {
    const h2 z = {(_Float16)0.f, (_Float16)0.f};
    h2 lo = __builtin_bit_cast(h2, pkh(d[0], d[1]));
    h2 hi = __builtin_bit_cast(h2, pkh(d[2], d[3]));
    lo = __builtin_elementwise_max(lo, z);
    hi = __builtin_elementwise_max(hi, z);
    int2 p;
    p.x = __builtin_bit_cast(int, lo);
    p.y = __builtin_bit_cast(int, hi);
    return __builtin_bit_cast(half4v, p);
}

// align-4 16B load (tile rows are dword- but not 16B-aligned: stride 13 dw)
__device__ __forceinline__ float4v ld4u(const float* p) {
    float4v r;
    __builtin_memcpy(&r, p, 16);
    return r;
}

__global__ __launch_bounds__(TPB)
__attribute__((amdgpu_waves_per_eu(4, 4)))
void mlp_kernel(const float* __restrict__ x,
                const float* __restrict__ W_in, const float* __restrict__ b_in,
                const float* __restrict__ W_h,  const float* __restrict__ b_h,
                const float* __restrict__ W_out,const float* __restrict__ b_out,
                float* __restrict__ out, int tiles)
{
    __shared__ unsigned lds[LDS_DW];
    const int tid = threadIdx.x;

    // ---- swizzle weights into f16 A-fragment layout in LDS (once/block) ----
    for (int s = tid; s < NL * 64; s += TPB) {
        const int L = s >> 6, ln = s & 63, m = ln & 15, gg = ln >> 4;
        float v[4];
#pragma unroll
        for (int i = 0; i < 4; ++i) {
            const int k = 4 * gg + i;
            if (L == 0)       v[i] = (k < S_IN) ? W_in[m * S_IN + k] : 0.f;
            else if (L <= 30) v[i] = W_h[(L - 1) * H * H + m * H + k];
            else              v[i] = (m == 0) ? W_out[k] : 0.f;
        }
        lds[s * 2]     = pkh(v[0], v[1]);
        lds[s * 2 + 1] = pkh(v[2], v[3]);
    }
    for (int s = tid; s < NL * H; s += TPB) {
        const int L = s >> 4, m = s & 15;
        float bv;
        if (L == 0)       bv = b_in[m];
        else if (L <= 30) bv = b_h[(L - 1) * H + m];
        else              bv = (m == 0) ? b_out[0] : 0.f;
        lds[4096 + s] = __float_as_uint(bv);
    }
    __syncthreads();

    const half4v* lA = (const half4v*)lds;             // [NL*64], 8B elems
    const float4v* lB = (const float4v*)(lds + 4096);  // [NL*4]

    const int lane = tid & 63;
    const int wv   = tid >> 6;
    const int g    = lane >> 4;
    const int col  = lane & 15;
    const bool edge = (col == 15) && (g == 3);         // lane 63: k0=12 overshoot
    const int goff = col * 13 + 4 * g - (edge ? 3 : 0);

    const int wave_id = blockIdx.x * WPB + wv;
    int tb = wave_id * T;
    if (tb >= tiles) return;

    float* op = out + (size_t)tb * 16 + lane;

    // prefetch first iteration's gathers (1 dwordx4 per lane per tile)
    const float* xp = x + (size_t)tb * 208 + goff;
    float4v v[T];
#pragma unroll
    for (int t = 0; t < T; ++t)
        v[t] = ld4u(xp + t * 208);

    for (; tb < tiles; tb += STRIDE) {
        // pack current inputs into B fragments
        half4v bf[T];
#pragma unroll
        for (int t = 0; t < T; ++t) {
            const float a0 = edge ? v[t][3] : v[t][0];
            const float a1 = edge ? 0.f : v[t][1];
            const float a2 = edge ? 0.f : v[t][2];
            const float a3 = edge ? 0.f : v[t][3];
            bf[t] = pack4h(a0, a1, a2, a3);
        }

        // issue next sweep's gathers now: in flight across the layer chain
        const int tbn = tb + STRIDE;
        if (tbn < tiles) {
            xp = x + (size_t)tbn * 208 + goff;
#pragma unroll
            for (int t = 0; t < T; ++t)
                v[t] = ld4u(xp + t * 208);
        }

        // ---- 31 layers, A/bias prefetched TWO ahead; bias rides in C ----
        half4v aC = lA[lane];              // layer 0
        half4v aN = lA[64 + lane];         // layer 1
        float4v cC = lB[g];
        float4v cN = lB[4 + g];
#pragma unroll
        for (int L = 0; L < NL - 1; ++L) {
            half4v aN2 = aN;
            float4v cN2 = cN;
            if (L + 2 < NL) {
                aN2 = lA[(L + 2) * 64 + lane];
                cN2 = lB[(L + 2) * 4 + g];
            }
#pragma unroll
            for (int t = 0; t < T; ++t) {
                float4v d = __builtin_amdgcn_mfma_f32_16x16x16f16(aC, bf[t], cC, 0, 0, 0);
                bf[t] = relu_pack4h(d);
            }
            aC = aN; aN = aN2;
            cC = cN; cN = cN2;
        }

        // output layer: W_out lives in row 0 only; y[n] = D[0][n]
#pragma unroll
        for (int t = 0; t < T; ++t) {
            float4v d = __builtin_amdgcn_mfma_f32_16x16x16f16(aC, bf[t], cC, 0, 0, 0);
            if (lane < 16) op[t * 16] = d[0];
        }
        op += (size_t)STRIDE * 16;
    }
}

extern "C" void kernel_launch(void* const* d_in, const int* in_sizes, int n_in,
                              void* d_out, int out_size, void* d_ws, size_t ws_size,
                              hipStream_t stream) {
    const float* x     = (const float*)d_in[0];
    const float* W_in  = (const float*)d_in[1];
    const float* b_in  = (const float*)d_in[2];
    const float* W_h   = (const float*)d_in[3];
    const float* b_h   = (const float*)d_in[4];
    const float* W_out = (const float*)d_in[5];
    const float* b_out = (const float*)d_in[6];
    float* out = (float*)d_out;

    const int tiles = out_size / 16;                       // 131072
    int blocks = (tiles + WPB * T - 1) / (WPB * T);
    if (blocks > NBLOCKS) blocks = NBLOCKS;
    mlp_kernel<<<blocks, TPB, 0, stream>>>(x, W_in, b_in, W_h, b_h, W_out, b_out,
                                           out, tiles);
}

// Round 5
// 266.418 us; speedup vs baseline: 1.1951x; 1.1951x over previous
//
#include <hip/hip_runtime.h>
#include <stdint.h>

// Batched tiny MLP [B,13]->16->(30x 16->16 relu)->1, fp32 in/out, f16 MFMA.
// Transposed formulation: mfma_f32_16x16x16_f16 D layout == B layout, so each
// layer's relu'd output is the next layer's B fragment in-register.
// R17: design for the REAL register budget. Evidence across R12/R15/R16:
// with MFMA present the backend splits the unified file evenly (cap 64 ->
// 32 arch, cap 128 -> 64 arch; R16's waves_per_eu(4,4) was honored -- SGPR
// 48->112 -- yet VGPR pinned at 64 and ~240MB scratch round-trip remained).
// Arch budget is 64, period. The only structure that can't fit is the
// cross-sweep prefetch v[8] (32 regs live across the 248-MFMA chain). So:
// (a) drop cross-sweep prefetch -- only 4 sweeps, ~900cy x4 unhidden worst
// case, mostly covered by 4 waves/SIMD TLP; (b) load+pack at loop head in
// TWO batches of 4 tiles (transient peak ~55 regs); (c) A/bias pipeline
// 2-ahead -> 1-ahead (saves 6 regs; ds_read ~120cy < ~130cy layer body).
// Steady live ~42-50 < 64 arch. Keep waves_per_eu(4,4) so split stays
// 64/64. Keeps R13 wins: direct coalesced gather (no LDS x round-trip,
// 0 bank conflicts), relu fused, T=8 chains for ILP.
// Floors: MFMA ~28us, memory ~19us. Target 45-65us dispatch.
// Edge case: lane(col=15,g=3) k0=12 gather would read 2 dwords past x's end
// on the last tile (x is exactly 2097152*52B). That lane loads shifted by -3
// dwords and selects v[3] as k=12, zeros for k>=13 (A rows 13..15 are zero,
// but garbage must be FINITE, so force 0).

typedef __attribute__((ext_vector_type(4))) _Float16 half4v;
typedef __attribute__((ext_vector_type(2))) _Float16 h2;
typedef __attribute__((ext_vector_type(4))) float float4v;

#define S_IN 13
#define H 16
#define NL 32            // mfma layers: 0 = input, 1..30 = hidden, 31 = output
#define TPB 512
#define WPB 8            // waves per block
#define T 8              // 16-sample tiles per wave per iteration
#define NBLOCKS 512      // 2 blocks/CU resident at 4 waves/EU
#define STRIDE (NBLOCKS * WPB * T)   // tiles per grid sweep = 32768

// LDS dword map (weights/bias only):
//   [0, 4096)     A-frags: 2 dwords (4 f16) per (L, lane)
//   [4096, 4608)  bias[L][m] fp32 (C-operand order)
#define LDS_DW 4608

__device__ __forceinline__ unsigned pkh(float a, float b) {
    return __builtin_bit_cast(unsigned, __builtin_amdgcn_cvt_pkrtz(a, b));
}

__device__ __forceinline__ half4v pack4h(float v0, float v1, float v2, float v3) {
    int2 p;
    p.x = (int)pkh(v0, v1);
    p.y = (int)pkh(v2, v3);
    return __builtin_bit_cast(half4v, p);
}

// cvt then packed-f16 relu: 2 cvt + 2 v_pk_max_f16
__device__ __forceinline__ half4v relu_pack4h(const float4v& d) {
    const h2 z = {(_Float16)0.f, (_Float16)0.f};
    h2 lo = __builtin_bit_cast(h2, pkh(d[0], d[1]));
    h2 hi = __builtin_bit_cast(h2, pkh(d[2], d[3]));
    lo = __builtin_elementwise_max(lo, z);
    hi = __builtin_elementwise_max(hi, z);
    int2 p;
    p.x = __builtin_bit_cast(int, lo);
    p.y = __builtin_bit_cast(int, hi);
    return __builtin_bit_cast(half4v, p);
}

// align-4 16B load (tile rows are dword- but not 16B-aligned: stride 13 dw)
__device__ __forceinline__ float4v ld4u(const float* p) {
    float4v r;
    __builtin_memcpy(&r, p, 16);
    return r;
}

__global__ __launch_bounds__(TPB)
__attribute__((amdgpu_waves_per_eu(4, 4)))
void mlp_kernel(const float* __restrict__ x,
                const float* __restrict__ W_in, const float* __restrict__ b_in,
                const float* __restrict__ W_h,  const float* __restrict__ b_h,
                const float* __restrict__ W_out,const float* __restrict__ b_out,
                float* __restrict__ out, int tiles)
{
    __shared__ unsigned lds[LDS_DW];
    const int tid = threadIdx.x;

    // ---- swizzle weights into f16 A-fragment layout in LDS (once/block) ----
    for (int s = tid; s < NL * 64; s += TPB) {
        const int L = s >> 6, ln = s & 63, m = ln & 15, gg = ln >> 4;
        float v[4];
#pragma unroll
        for (int i = 0; i < 4; ++i) {
            const int k = 4 * gg + i;
            if (L == 0)       v[i] = (k < S_IN) ? W_in[m * S_IN + k] : 0.f;
            else if (L <= 30) v[i] = W_h[(L - 1) * H * H + m * H + k];
            else              v[i] = (m == 0) ? W_out[k] : 0.f;
        }
        lds[s * 2]     = pkh(v[0], v[1]);
        lds[s * 2 + 1] = pkh(v[2], v[3]);
    }
    for (int s = tid; s < NL * H; s += TPB) {
        const int L = s >> 4, m = s & 15;
        float bv;
        if (L == 0)       bv = b_in[m];
        else if (L <= 30) bv = b_h[(L - 1) * H + m];
        else              bv = (m == 0) ? b_out[0] : 0.f;
        lds[4096 + s] = __float_as_uint(bv);
    }
    __syncthreads();

    const half4v* lA = (const half4v*)lds;             // [NL*64], 8B elems
    const float4v* lB = (const float4v*)(lds + 4096);  // [NL*4]

    const int lane = tid & 63;
    const int wv   = tid >> 6;
    const int g    = lane >> 4;
    const int col  = lane & 15;
    const bool edge = (col == 15) && (g == 3);         // lane 63: k0=12 overshoot
    const int goff = col * 13 + 4 * g - (edge ? 3 : 0);

    const int wave_id = blockIdx.x * WPB + wv;
    int tb = wave_id * T;
    if (tb >= tiles) return;

    float* op = out + (size_t)tb * 16 + lane;

    for (; tb < tiles; tb += STRIDE) {
        // ---- gather + pack, two batches of 4 tiles (short live ranges) ----
        const float* xp = x + (size_t)tb * 208 + goff;
        half4v bf[T];
#pragma unroll
        for (int half = 0; half < 2; ++half) {
            float4v v0 = ld4u(xp + (half * 4 + 0) * 208);
            float4v v1 = ld4u(xp + (half * 4 + 1) * 208);
            float4v v2 = ld4u(xp + (half * 4 + 2) * 208);
            float4v v3 = ld4u(xp + (half * 4 + 3) * 208);
            bf[half * 4 + 0] = pack4h(edge ? v0[3] : v0[0], edge ? 0.f : v0[1],
                                      edge ? 0.f : v0[2],  edge ? 0.f : v0[3]);
            bf[half * 4 + 1] = pack4h(edge ? v1[3] : v1[0], edge ? 0.f : v1[1],
                                      edge ? 0.f : v1[2],  edge ? 0.f : v1[3]);
            bf[half * 4 + 2] = pack4h(edge ? v2[3] : v2[0], edge ? 0.f : v2[1],
                                      edge ? 0.f : v2[2],  edge ? 0.f : v2[3]);
            bf[half * 4 + 3] = pack4h(edge ? v3[3] : v3[0], edge ? 0.f : v3[1],
                                      edge ? 0.f : v3[2],  edge ? 0.f : v3[3]);
        }

        // ---- 31 layers, A/bias prefetched ONE ahead; bias rides in C ----
        half4v aC = lA[lane];              // layer 0
        float4v cC = lB[g];
#pragma unroll
        for (int L = 0; L < NL - 1; ++L) {
            half4v aN = lA[(L + 1) * 64 + lane];
            float4v cN = lB[(L + 1) * 4 + g];
#pragma unroll
            for (int t = 0; t < T; ++t) {
                float4v d = __builtin_amdgcn_mfma_f32_16x16x16f16(aC, bf[t], cC, 0, 0, 0);
                bf[t] = relu_pack4h(d);
            }
            aC = aN;
            cC = cN;
        }

        // output layer: W_out lives in row 0 only; y[n] = D[0][n]
#pragma unroll
        for (int t = 0; t < T; ++t) {
            float4v d = __builtin_amdgcn_mfma_f32_16x16x16f16(aC, bf[t], cC, 0, 0, 0);
            if (lane < 16) op[t * 16] = d[0];
        }
        op += (size_t)STRIDE * 16;
    }
}

extern "C" void kernel_launch(void* const* d_in, const int* in_sizes, int n_in,
                              void* d_out, int out_size, void* d_ws, size_t ws_size,
                              hipStream_t stream) {
    const float* x     = (const float*)d_in[0];
    const float* W_in  = (const float*)d_in[1];
    const float* b_in  = (const float*)d_in[2];
    const float* W_h   = (const float*)d_in[3];
    const float* b_h   = (const float*)d_in[4];
    const float* W_out = (const float*)d_in[5];
    const float* b_out = (const float*)d_in[6];
    float* out = (float*)d_out;

    const int tiles = out_size / 16;                       // 131072
    int blocks = (tiles + WPB * T - 1) / (WPB * T);
    if (blocks > NBLOCKS) blocks = NBLOCKS;
    mlp_kernel<<<blocks, TPB, 0, stream>>>(x, W_in, b_in, W_h, b_h, W_out, b_out,
                                           out, tiles);
}

// Round 6
// 193.628 us; speedup vs baseline: 1.6443x; 1.3759x over previous
//
#include <hip/hip_runtime.h>
#include <stdint.h>

// Batched tiny MLP [B,13]->16->(30x 16->16 relu)->1, fp32 in/out, f16 MFMA.
// Transposed formulation: mfma_f32_16x16x16_f16 D layout == B layout, so each
// layer's relu'd output is the next layer's B fragment in-register.
// R18: stop the scheduler's live-range explosion. R17 still spilled ~28
// dwords/lane-iter (WRITE 124MB vs 8.4MB real) despite a ~45-reg steady
// live set. Cause: the 31-layer loop was FULLY UNROLLED (248 MFMAs straight
// line) -- the scheduler hoists lA/lB ds_reads far ahead of their layers,
// inflating live ranges until bf/v spill. Fix: roll the layer loop
// (#pragma unroll 1). Loop-carried: bf[8]=16 + aC=2 + cC=4 + 1-ahead
// aN/cN=6 + addr ~12 = ~40 regs; gather transient peak ~56 < 64 arch.
// Body (8 MFMA + 32 VALU ~ 130cy) covers next layer's ds_read (~120cy).
// Low pressure also lets MFMA C/D live in arch VGPRs (gfx950 unified file)
// => no v_accvgpr_read on the relu path. Keep waves_per_eu(4,4) (128-reg
// unified cap, 4 waves/SIMD), direct coalesced gather, fused relu, T=8.
// Floors: MFMA ~28us chain-issue, memory ~19us. Target 35-60us dispatch.
// Edge case: lane(col=15,g=3) k0=12 gather would read 2 dwords past x's end
// on the last tile (x is exactly 2097152*52B). That lane loads shifted by -3
// dwords and selects v[3] as k=12, zeros for k>=13 (A rows 13..15 are zero,
// but garbage must be FINITE, so force 0).

typedef __attribute__((ext_vector_type(4))) _Float16 half4v;
typedef __attribute__((ext_vector_type(2))) _Float16 h2;
typedef __attribute__((ext_vector_type(4))) float float4v;

#define S_IN 13
#define H 16
#define NL 32            // mfma layers: 0 = input, 1..30 = hidden, 31 = output
#define TPB 512
#define WPB 8            // waves per block
#define T 8              // 16-sample tiles per wave per iteration
#define NBLOCKS 512      // fills 1024 SIMDs at 4 waves/SIMD
#define STRIDE (NBLOCKS * WPB * T)   // tiles per grid sweep = 32768

// LDS dword map (weights/bias only):
//   [0, 4096)     A-frags: 2 dwords (4 f16) per (L, lane)
//   [4096, 4608)  bias[L][m] fp32 (C-operand order)
#define LDS_DW 4608

__device__ __forceinline__ unsigned pkh(float a, float b) {
    return __builtin_bit_cast(unsigned, __builtin_amdgcn_cvt_pkrtz(a, b));
}

__device__ __forceinline__ half4v pack4h(float v0, float v1, float v2, float v3) {
    int2 p;
    p.x = (int)pkh(v0, v1);
    p.y = (int)pkh(v2, v3);
    return __builtin_bit_cast(half4v, p);
}

// cvt then packed-f16 relu: 2 cvt + 2 v_pk_max_f16
__device__ __forceinline__ half4v relu_pack4h(const float4v& d) {
    const h2 z = {(_Float16)0.f, (_Float16)0.f};
    h2 lo = __builtin_bit_cast(h2, pkh(d[0], d[1]));
    h2 hi = __builtin_bit_cast(h2, pkh(d[2], d[3]));
    lo = __builtin_elementwise_max(lo, z);
    hi = __builtin_elementwise_max(hi, z);
    int2 p;
    p.x = __builtin_bit_cast(int, lo);
    p.y = __builtin_bit_cast(int, hi);
    return __builtin_bit_cast(half4v, p);
}

// align-4 16B load (tile rows are dword- but not 16B-aligned: stride 13 dw)
__device__ __forceinline__ float4v ld4u(const float* p) {
    float4v r;
    __builtin_memcpy(&r, p, 16);
    return r;
}

__global__ __launch_bounds__(TPB)
__attribute__((amdgpu_waves_per_eu(4, 4)))
void mlp_kernel(const float* __restrict__ x,
                const float* __restrict__ W_in, const float* __restrict__ b_in,
                const float* __restrict__ W_h,  const float* __restrict__ b_h,
                const float* __restrict__ W_out,const float* __restrict__ b_out,
                float* __restrict__ out, int tiles)
{
    __shared__ unsigned lds[LDS_DW];
    const int tid = threadIdx.x;

    // ---- swizzle weights into f16 A-fragment layout in LDS (once/block) ----
    for (int s = tid; s < NL * 64; s += TPB) {
        const int L = s >> 6, ln = s & 63, m = ln & 15, gg = ln >> 4;
        float v[4];
#pragma unroll
        for (int i = 0; i < 4; ++i) {
            const int k = 4 * gg + i;
            if (L == 0)       v[i] = (k < S_IN) ? W_in[m * S_IN + k] : 0.f;
            else if (L <= 30) v[i] = W_h[(L - 1) * H * H + m * H + k];
            else              v[i] = (m == 0) ? W_out[k] : 0.f;
        }
        lds[s * 2]     = pkh(v[0], v[1]);
        lds[s * 2 + 1] = pkh(v[2], v[3]);
    }
    for (int s = tid; s < NL * H; s += TPB) {
        const int L = s >> 4, m = s & 15;
        float bv;
        if (L == 0)       bv = b_in[m];
        else if (L <= 30) bv = b_h[(L - 1) * H + m];
        else              bv = (m == 0) ? b_out[0] : 0.f;
        lds[4096 + s] = __float_as_uint(bv);
    }
    __syncthreads();

    const half4v* lA = (const half4v*)lds;             // [NL*64], 8B elems
    const float4v* lB = (const float4v*)(lds + 4096);  // [NL*4]

    const int lane = tid & 63;
    const int wv   = tid >> 6;
    const int g    = lane >> 4;
    const int col  = lane & 15;
    const bool edge = (col == 15) && (g == 3);         // lane 63: k0=12 overshoot
    const int goff = col * 13 + 4 * g - (edge ? 3 : 0);

    const int wave_id = blockIdx.x * WPB + wv;
    int tb = wave_id * T;
    if (tb >= tiles) return;

    float* op = out + (size_t)tb * 16 + lane;

    for (; tb < tiles; tb += STRIDE) {
        // ---- gather + pack, two batches of 4 tiles (short live ranges) ----
        const float* xp = x + (size_t)tb * 208 + goff;
        half4v bf[T];
#pragma unroll
        for (int half = 0; half < 2; ++half) {
            float4v v0 = ld4u(xp + (half * 4 + 0) * 208);
            float4v v1 = ld4u(xp + (half * 4 + 1) * 208);
            float4v v2 = ld4u(xp + (half * 4 + 2) * 208);
            float4v v3 = ld4u(xp + (half * 4 + 3) * 208);
            bf[half * 4 + 0] = pack4h(edge ? v0[3] : v0[0], edge ? 0.f : v0[1],
                                      edge ? 0.f : v0[2],  edge ? 0.f : v0[3]);
            bf[half * 4 + 1] = pack4h(edge ? v1[3] : v1[0], edge ? 0.f : v1[1],
                                      edge ? 0.f : v1[2],  edge ? 0.f : v1[3]);
            bf[half * 4 + 2] = pack4h(edge ? v2[3] : v2[0], edge ? 0.f : v2[1],
                                      edge ? 0.f : v2[2],  edge ? 0.f : v2[3]);
            bf[half * 4 + 3] = pack4h(edge ? v3[3] : v3[0], edge ? 0.f : v3[1],
                                      edge ? 0.f : v3[2],  edge ? 0.f : v3[3]);
        }

        // ---- 31 layers, ROLLED loop (bounded live ranges), 1-ahead A/bias ----
        half4v aC = lA[lane];              // layer 0
        float4v cC = lB[g];
#pragma unroll 1
        for (int L = 0; L < NL - 1; ++L) {
            half4v aN = lA[(L + 1) * 64 + lane];
            float4v cN = lB[(L + 1) * 4 + g];
#pragma unroll
            for (int t = 0; t < T; ++t) {
                float4v d = __builtin_amdgcn_mfma_f32_16x16x16f16(aC, bf[t], cC, 0, 0, 0);
                bf[t] = relu_pack4h(d);
            }
            aC = aN;
            cC = cN;
        }

        // output layer: W_out lives in row 0 only; y[n] = D[0][n]
#pragma unroll
        for (int t = 0; t < T; ++t) {
            float4v d = __builtin_amdgcn_mfma_f32_16x16x16f16(aC, bf[t], cC, 0, 0, 0);
            if (lane < 16) op[t * 16] = d[0];
        }
        op += (size_t)STRIDE * 16;
    }
}

extern "C" void kernel_launch(void* const* d_in, const int* in_sizes, int n_in,
                              void* d_out, int out_size, void* d_ws, size_t ws_size,
                              hipStream_t stream) {
    const float* x     = (const float*)d_in[0];
    const float* W_in  = (const float*)d_in[1];
    const float* b_in  = (const float*)d_in[2];
    const float* W_h   = (const float*)d_in[3];
    const float* b_h   = (const float*)d_in[4];
    const float* W_out = (const float*)d_in[5];
    const float* b_out = (const float*)d_in[6];
    float* out = (float*)d_out;

    const int tiles = out_size / 16;                       // 131072
    int blocks = (tiles + WPB * T - 1) / (WPB * T);
    if (blocks > NBLOCKS) blocks = NBLOCKS;
    mlp_kernel<<<blocks, TPB, 0, stream>>>(x, W_in, b_in, W_h, b_h, W_out, b_out,
                                           out, tiles);
}

// Round 8
// 191.155 us; speedup vs baseline: 1.6656x; 1.0129x over previous
//
#include <hip/hip_runtime.h>
#include <stdint.h>

// Batched tiny MLP [B,13]->16->(30x 16->16 relu)->1, fp32 in/out, f16 MFMA.
// Transposed formulation: mfma_f32_16x16x16_f16 D layout == B layout, so each
// layer's relu'd output is the next layer's B fragment in-register.
// R20 == R19 resubmit (container infra failure, same signature as R1/R14:
// no compile/pytest output ever produced; kernel re-audited: pipeline
// dataflow correct, OOB-clean, hang-free, graph-capture-safe).
// R19: intra-wave MFMA||VALU software pipeline. Evidence: R12 (75us, 57% occ,
// LDS-staged x, 2-ahead) == R18 (77us, 31% occ, direct gather, 1-ahead, NO
// spill) -- both 45cyc/SIMD/tile-layer, MfmaUtil ~36%. Occupancy & memory
// path don't matter => limiter is the shared per-layer phase-serial chain:
// [8xMFMA burst] -> [8xrelu burst] -> next layer, ~200cyc serial per layer,
// and cross-wave interleave demonstrably doesn't fill the pipes. Fix: split
// T=8 into 2 groups of 4, pipelined HALF A LAYER apart so one group's relu
// (VALU) runs under the other group's MFMAs:
//   steady layer L: [MFMA g0(L)] [relu g1(L-1) + A/bias prefetch]
//                   [MFMA g1(L)] [relu g0(L)]
// Every consumer >=16 instrs from its producer (no hazard stalls); per layer
// ~max(130 MFMA-pipe, 64 VALU) ~= 130cy -> 16.2cy/tile-layer = MFMA floor.
// d0/d1 are MFMA C/D (expected AGPR-half residents; gfx90a+ VALU reads AGPR
// directly, no bounce). WRITE_SIZE is the spill canary (stay ~8.2MB).
// Keeps R18's proven-clean parts: rolled layer loop (#pragma unroll 1),
// direct coalesced dwordx4 gather, 18KB LDS, waves_per_eu(4,4).
// Edge case: lane(col=15,g=3) k0=12 gather would read 2 dwords past x's end
// on the last tile (x is exactly 2097152*52B). That lane loads shifted by -3
// dwords and selects v[3] as k=12, zeros for k>=13.

typedef __attribute__((ext_vector_type(4))) _Float16 half4v;
typedef __attribute__((ext_vector_type(2))) _Float16 h2;
typedef __attribute__((ext_vector_type(4))) float float4v;

#define S_IN 13
#define H 16
#define NL 32            // mfma layers: 0 = input, 1..30 = hidden, 31 = output
#define TPB 512
#define WPB 8            // waves per block
#define T 8              // 16-sample tiles per wave per iteration (2 groups of 4)
#define NBLOCKS 512      // fills 1024 SIMDs at 4 waves/SIMD
#define STRIDE (NBLOCKS * WPB * T)   // tiles per grid sweep = 32768

// LDS dword map (weights/bias only):
//   [0, 4096)     A-frags: 2 dwords (4 f16) per (L, lane)
//   [4096, 4608)  bias[L][m] fp32 (C-operand order)
#define LDS_DW 4608

__device__ __forceinline__ unsigned pkh(float a, float b) {
    return __builtin_bit_cast(unsigned, __builtin_amdgcn_cvt_pkrtz(a, b));
}

__device__ __forceinline__ half4v pack4h(float v0, float v1, float v2, float v3) {
    int2 p;
    p.x = (int)pkh(v0, v1);
    p.y = (int)pkh(v2, v3);
    return __builtin_bit_cast(half4v, p);
}

// cvt then packed-f16 relu: 2 cvt + 2 v_pk_max_f16
__device__ __forceinline__ half4v relu_pack4h(const float4v& d) {
    const h2 z = {(_Float16)0.f, (_Float16)0.f};
    h2 lo = __builtin_bit_cast(h2, pkh(d[0], d[1]));
    h2 hi = __builtin_bit_cast(h2, pkh(d[2], d[3]));
    lo = __builtin_elementwise_max(lo, z);
    hi = __builtin_elementwise_max(hi, z);
    int2 p;
    p.x = __builtin_bit_cast(int, lo);
    p.y = __builtin_bit_cast(int, hi);
    return __builtin_bit_cast(half4v, p);
}

// align-4 16B load (tile rows are dword- but not 16B-aligned: stride 13 dw)
__device__ __forceinline__ float4v ld4u(const float* p) {
    float4v r;
    __builtin_memcpy(&r, p, 16);
    return r;
}

__global__ __launch_bounds__(TPB)
__attribute__((amdgpu_waves_per_eu(4, 4)))
void mlp_kernel(const float* __restrict__ x,
                const float* __restrict__ W_in, const float* __restrict__ b_in,
                const float* __restrict__ W_h,  const float* __restrict__ b_h,
                const float* __restrict__ W_out,const float* __restrict__ b_out,
                float* __restrict__ out, int tiles)
{
    __shared__ unsigned lds[LDS_DW];
    const int tid = threadIdx.x;

    // ---- swizzle weights into f16 A-fragment layout in LDS (once/block) ----
    for (int s = tid; s < NL * 64; s += TPB) {
        const int L = s >> 6, ln = s & 63, m = ln & 15, gg = ln >> 4;
        float v[4];
#pragma unroll
        for (int i = 0; i < 4; ++i) {
            const int k = 4 * gg + i;
            if (L == 0)       v[i] = (k < S_IN) ? W_in[m * S_IN + k] : 0.f;
            else if (L <= 30) v[i] = W_h[(L - 1) * H * H + m * H + k];
            else              v[i] = (m == 0) ? W_out[k] : 0.f;
        }
        lds[s * 2]     = pkh(v[0], v[1]);
        lds[s * 2 + 1] = pkh(v[2], v[3]);
    }
    for (int s = tid; s < NL * H; s += TPB) {
        const int L = s >> 4, m = s & 15;
        float bv;
        if (L == 0)       bv = b_in[m];
        else if (L <= 30) bv = b_h[(L - 1) * H + m];
        else              bv = (m == 0) ? b_out[0] : 0.f;
        lds[4096 + s] = __float_as_uint(bv);
    }
    __syncthreads();

    const half4v* lA = (const half4v*)lds;             // [NL*64], 8B elems
    const float4v* lB = (const float4v*)(lds + 4096);  // [NL*4]

    const int lane = tid & 63;
    const int wv   = tid >> 6;
    const int g    = lane >> 4;
    const int col  = lane & 15;
    const bool edge = (col == 15) && (g == 3);         // lane 63: k0=12 overshoot
    const int goff = col * 13 + 4 * g - (edge ? 3 : 0);

    const int wave_id = blockIdx.x * WPB + wv;
    int tb = wave_id * T;
    if (tb >= tiles) return;

    float* op = out + (size_t)tb * 16 + lane;

    for (; tb < tiles; tb += STRIDE) {
        // ---- gather + pack, two batches of 4 tiles (short live ranges) ----
        const float* xp = x + (size_t)tb * 208 + goff;
        half4v bf[T];
#pragma unroll
        for (int half = 0; half < 2; ++half) {
            float4v v0 = ld4u(xp + (half * 4 + 0) * 208);
            float4v v1 = ld4u(xp + (half * 4 + 1) * 208);
            float4v v2 = ld4u(xp + (half * 4 + 2) * 208);
            float4v v3 = ld4u(xp + (half * 4 + 3) * 208);
            bf[half * 4 + 0] = pack4h(edge ? v0[3] : v0[0], edge ? 0.f : v0[1],
                                      edge ? 0.f : v0[2],  edge ? 0.f : v0[3]);
            bf[half * 4 + 1] = pack4h(edge ? v1[3] : v1[0], edge ? 0.f : v1[1],
                                      edge ? 0.f : v1[2],  edge ? 0.f : v1[3]);
            bf[half * 4 + 2] = pack4h(edge ? v2[3] : v2[0], edge ? 0.f : v2[1],
                                      edge ? 0.f : v2[2],  edge ? 0.f : v2[3]);
            bf[half * 4 + 3] = pack4h(edge ? v3[3] : v3[0], edge ? 0.f : v3[1],
                                      edge ? 0.f : v3[2],  edge ? 0.f : v3[3]);
        }

        // ---- layer 0 prologue: fill the pipeline ----
        half4v aC = lA[lane];
        float4v cC = lB[g];
        half4v aN = lA[64 + lane];
        float4v cN = lB[4 + g];
        float4v d0[4], d1[4];
#pragma unroll
        for (int t = 0; t < 4; ++t)
            d0[t] = __builtin_amdgcn_mfma_f32_16x16x16f16(aC, bf[t], cC, 0, 0, 0);
#pragma unroll
        for (int t = 0; t < 4; ++t)
            d1[t] = __builtin_amdgcn_mfma_f32_16x16x16f16(aC, bf[4 + t], cC, 0, 0, 0);
#pragma unroll
        for (int t = 0; t < 4; ++t)
            bf[t] = relu_pack4h(d0[t]);
        aC = aN; cC = cN;

        // ---- layers 1..30: 4-phase pipeline, groups half a layer apart ----
        // invariant at top: bf[0..3]=relu'd L-1 outputs; d1=raw L-1 outputs g1
#pragma unroll 1
        for (int L = 1; L < NL - 1; ++L) {
            // phase 1: MFMA group 0 of layer L
#pragma unroll
            for (int t = 0; t < 4; ++t)
                d0[t] = __builtin_amdgcn_mfma_f32_16x16x16f16(aC, bf[t], cC, 0, 0, 0);
            // phase 2: relu group 1 of layer L-1 (VALU under phase-1 MFMAs)
            aN = lA[(L + 1) * 64 + lane];
            cN = lB[(L + 1) * 4 + g];
#pragma unroll
            for (int t = 0; t < 4; ++t)
                bf[4 + t] = relu_pack4h(d1[t]);
            // phase 3: MFMA group 1 of layer L
#pragma unroll
            for (int t = 0; t < 4; ++t)
                d1[t] = __builtin_amdgcn_mfma_f32_16x16x16f16(aC, bf[4 + t], cC, 0, 0, 0);
            // phase 4: relu group 0 of layer L (VALU under phase-3 MFMAs)
#pragma unroll
            for (int t = 0; t < 4; ++t)
                bf[t] = relu_pack4h(d0[t]);
            aC = aN; cC = cN;
        }

        // ---- output layer 31: W_out row 0 only; y[n] = D[0][n] ----
#pragma unroll
        for (int t = 0; t < 4; ++t) {
            float4v d = __builtin_amdgcn_mfma_f32_16x16x16f16(aC, bf[t], cC, 0, 0, 0);
            if (lane < 16) op[t * 16] = d[0];
        }
#pragma unroll
        for (int t = 0; t < 4; ++t)
            bf[4 + t] = relu_pack4h(d1[t]);
#pragma unroll
        for (int t = 0; t < 4; ++t) {
            float4v d = __builtin_amdgcn_mfma_f32_16x16x16f16(aC, bf[4 + t], cC, 0, 0, 0);
            if (lane < 16) op[(4 + t) * 16] = d[0];
        }
        op += (size_t)STRIDE * 16;
    }
}

extern "C" void kernel_launch(void* const* d_in, const int* in_sizes, int n_in,
                              void* d_out, int out_size, void* d_ws, size_t ws_size,
                              hipStream_t stream) {
    const float* x     = (const float*)d_in[0];
    const float* W_in  = (const float*)d_in[1];
    const float* b_in  = (const float*)d_in[2];
    const float* W_h   = (const float*)d_in[3];
    const float* b_h   = (const float*)d_in[4];
    const float* W_out = (const float*)d_in[5];
    const float* b_out = (const float*)d_in[6];
    float* out = (float*)d_out;

    const int tiles = out_size / 16;                       // 131072
    int blocks = (tiles + WPB * T - 1) / (WPB * T);
    if (blocks > NBLOCKS) blocks = NBLOCKS;
    mlp_kernel<<<blocks, TPB, 0, stream>>>(x, W_in, b_in, W_h, b_h, W_out, b_out,
                                           out, tiles);
}